// Round 23
// baseline (84.266 us; speedup 1.0000x reference)
//
#include <hip/hip_runtime.h>
#include <math.h>

#define NUM_E 6
#define DIM 1024
#define HID 256
#define NTOK 32768
#define NPB 4096   // tokens per batch (N)
#define TTYPE_UNKNOWN 5
#define ONE_MINUS_ALPHA 0.775f
#define FLOOR_TERM 0.0375f     // alpha * (1/E)
#define GRPM 8                 // real tokens per MFMA block (A rows 8..15 zero)
#define EPS_GAP 4e-5f          // top-2 prob gap below which fp32 recheck runs

// workspace layout (bytes)
#define WS_CNT   0
#define WS_CNT2  64
#define WS_LIST  256
#define WS_LIST2 (256 + 131072)
#define WS_WFH   (512 * 1024)          // W1 bf16 (RNE), fragment-swizzled (512 KB)
#define WS_NEED  ((size_t)(1024 * 1024))

typedef __attribute__((ext_vector_type(8))) short short8;
typedef __attribute__((ext_vector_type(4))) float f32x4;

__device__ __forceinline__ unsigned short rne_bf16(float f) {
    unsigned int u = __float_as_uint(f);
    return (unsigned short)((u + 0x7FFFu + ((u >> 16) & 1u)) >> 16);
}

// Closed-form top1 + hard-cap + combine for a probs vector of 6.
__device__ __forceinline__ void finalize_and_write(const float probs[NUM_E], float cap,
                                                   float* __restrict__ disp_out,
                                                   float* __restrict__ comb_out) {
    float v = probs[0];
    int bi = 0;
#pragma unroll
    for (int e = 1; e < NUM_E; ++e) {
        if (probs[e] > v) { v = probs[e]; bi = e; }
    }
    float excess = fmaxf(v - cap, 0.0f);
    float capped = v - excess;                 // min(v, cap)
    float hr_idx = fmaxf(cap - capped, 0.0f);
    float hsum = fmaxf(hr_idx + 5.0f * cap, 1e-8f);
    float disp[NUM_E];
    float other = excess * cap / hsum;
#pragma unroll
    for (int e = 0; e < NUM_E; ++e) disp[e] = other;
    disp[bi] = capped + excess * hr_idx / hsum;
    float s = 0.0f;
#pragma unroll
    for (int e = 0; e < NUM_E; ++e) s += disp[e];
    float inv = 1.0f / (s + 1e-8f);
#pragma unroll
    for (int e = 0; e < NUM_E; ++e) {
        disp_out[e] = disp[e];
        comb_out[e] = disp[e] * inv;
    }
}

// Known tokens -> final output directly; unknown -> compacted list.
__launch_bounds__(256)
__global__ void classify_kernel(const int* __restrict__ ttypes,
                                const int* __restrict__ tarr,
                                const float* __restrict__ base,
                                float* __restrict__ out,
                                int* __restrict__ cnt,
                                int* __restrict__ list) {
    int i = blockIdx.x * blockDim.x + threadIdx.x;
    if (i >= NTOK) return;
    int ty = ttypes[i];
    if (ty == TTYPE_UNKNOWN) {
        int pos = atomicAdd(cnt, 1);
        list[pos] = i;
        return;
    }
    int b = i / NPB;
    float tnorm = (float)tarr[b] / 1000.0f;
    float cap = 0.5f + 1.1f * tnorm;
    float probs[NUM_E];
#pragma unroll
    for (int e = 0; e < NUM_E; ++e)
        probs[e] = ONE_MINUS_ALPHA * base[ty * NUM_E + e] + FLOOR_TERM;
    finalize_and_write(probs, cap,
                       out + (size_t)i * NUM_E,
                       out + (size_t)NTOK * NUM_E + (size_t)i * NUM_E);
}

// W1 -> bf16 (RNE), swizzled to MFMA B-fragment order:
// wfh[((t*4+g)*256 + col)*8 + j] = bf16(W1[(t*32+g*8+j)][col]).
__launch_bounds__(256)
__global__ void prep_w1(const float* __restrict__ W1,
                        unsigned short* __restrict__ wfh) {
    int idx = blockIdx.x * 256 + threadIdx.x;   // 128 x 256 = 32768
    int tg = idx >> 8;                          // (t*4+g) in [0,128)
    int col = idx & 255;
    int kbase = (tg >> 2) * 32 + (tg & 3) * 8;
    unsigned int hw[4];
#pragma unroll
    for (int p = 0; p < 4; ++p) {
        unsigned int lo = rne_bf16(W1[(size_t)(kbase + 2 * p) * HID + col]);
        unsigned int hi = rne_bf16(W1[(size_t)(kbase + 2 * p + 1) * HID + col]);
        hw[p] = lo | (hi << 16);
    }
    size_t off = ((size_t)tg * 256 + col) * 8;
    *reinterpret_cast<uint4*>(wfh + off) = make_uint4(hw[0], hw[1], hw[2], hw[3]);
}

// MFMA MLP: 512 threads = 8 waves, GRPM=8 real tokens/block (683 working
// blocks -> ~5.3 waves/SIMD, 2x R22). A rows 8..15 zero-filled (zeros
// through MFMA are exact). Per t-iter: 1 ds_read + 2 global dwordx4 + 2 MFMA,
// unroll-4 -> 8 W loads in flight. Verified fragment mappings from R21/R22.
__launch_bounds__(512)
__global__ void mfma_mlp(const float* __restrict__ tokens,
                         const int* __restrict__ tarr,
                         const unsigned short* __restrict__ wfh,
                         const float* __restrict__ b1,
                         const float* __restrict__ W2,
                         const float* __restrict__ b2,
                         float* __restrict__ out,
                         const int* __restrict__ cnt,
                         const int* __restrict__ list,
                         int* __restrict__ cnt2,
                         int* __restrict__ list2) {
    __shared__ unsigned short xh[16][DIM];     // 32 KB; hs aliases after K-loop
    __shared__ float w2s[HID * NUM_E];         // 6 KB
    __shared__ float ls[GRPM][NUM_E];

    int count = cnt[0];
    int start = blockIdx.x * GRPM;
    if (count == 0 || start >= count) return;
    int tid = threadIdx.x;

    // Stage 8 real rows (batched: 4 loads issued, then split/store) and
    // zero rows 8..15.
    {
        int slot = tid & 255;
        int half = tid >> 8;
        float4 v[4];
#pragma unroll
        for (int p = 0; p < 4; ++p) {
            int r = p * 2 + half;              // 0..7
            int idx = start + r;
            if (idx > count - 1) idx = count - 1;   // dup tail -> idempotent
            int tok = list[idx];
            v[p] = reinterpret_cast<const float4*>(tokens + (size_t)tok * DIM)[slot];
        }
#pragma unroll
        for (int p = 0; p < 4; ++p) {
            int r = p * 2 + half;
            ushort4 h4 = make_ushort4(rne_bf16(v[p].x), rne_bf16(v[p].y),
                                      rne_bf16(v[p].z), rne_bf16(v[p].w));
            *reinterpret_cast<ushort4*>(&xh[r][slot * 4]) = h4;
        }
#pragma unroll
        for (int p = 0; p < 4; ++p) {
            int r = 8 + p * 2 + half;          // 8..15
            *reinterpret_cast<ushort4*>(&xh[r][slot * 4]) = make_ushort4(0, 0, 0, 0);
        }
    }
    for (int kk = tid; kk < HID * NUM_E; kk += 512) w2s[kk] = W2[kk];
    __syncthreads();

    int lane = tid & 63;
    int wv = tid >> 6;                  // 0..7
    int arow = lane & 15;               // A row
    int grp = lane >> 4;                // k-group 0..3

    f32x4 acc[2];
    acc[0] = (f32x4){0.f, 0.f, 0.f, 0.f};
    acc[1] = (f32x4){0.f, 0.f, 0.f, 0.f};
    int colg[2];
    colg[0] = wv * 32 + (lane & 15);
    colg[1] = wv * 32 + 16 + (lane & 15);

#pragma unroll 4
    for (int t = 0; t < DIM / 32; ++t) {
        short8 ah = *reinterpret_cast<const short8*>(&xh[arow][t * 32 + grp * 8]);
        size_t b0 = ((size_t)(t * 4 + grp) * 256 + colg[0]) * 8;
        size_t b1o = ((size_t)(t * 4 + grp) * 256 + colg[1]) * 8;
        short8 bh0 = *reinterpret_cast<const short8*>(wfh + b0);
        short8 bh1 = *reinterpret_cast<const short8*>(wfh + b1o);
        acc[0] = __builtin_amdgcn_mfma_f32_16x16x32_bf16(ah, bh0, acc[0], 0, 0, 0);
        acc[1] = __builtin_amdgcn_mfma_f32_16x16x32_bf16(ah, bh1, acc[1], 0, 0, 0);
    }
    __syncthreads();   // all xh reads done; alias hs over xh

    float (*hs)[HID] = (float (*)[HID])xh;   // rows 0..7 used
    const float kc = 0.70710678118654752f;
#pragma unroll
    for (int c = 0; c < 2; ++c) {
        float bb = b1[colg[c]];
#pragma unroll
        for (int i = 0; i < 4; ++i) {
            int row = grp * 4 + i;              // D row = (lane>>4)*4 + reg (m89)
            if (row < GRPM) {
                float pre = acc[c][i] + bb;
                hs[row][colg[c]] = 0.5f * pre * (1.0f + erff(pre * kc));
            }
        }
    }
    __syncthreads();

    // Layer 2: 48 threads, one (token, expert) dot each
    if (tid < GRPM * NUM_E) {
        int r = tid / NUM_E, e = tid % NUM_E;
        float s = 0.0f;
        for (int j = 0; j < HID; ++j) s = fmaf(hs[r][j], w2s[j * NUM_E + e], s);
        ls[r][e] = (s + b2[e]) / 0.1f;   // temperature
    }
    __syncthreads();

    // Finalize + near-tie flagging
    if (tid < GRPM && start + tid < count) {
        int tokidx = list[start + tid];
        int b = tokidx / NPB;
        float tnorm = (float)tarr[b] / 1000.0f;
        float cap = 0.5f + 1.1f * tnorm;
        float probs[NUM_E];
#pragma unroll
        for (int e = 0; e < NUM_E; ++e)
            probs[e] = ONE_MINUS_ALPHA * ls[tid][e] + FLOOR_TERM;
        float v1 = -1e30f, v2 = -1e30f;
#pragma unroll
        for (int e = 0; e < NUM_E; ++e) {
            if (probs[e] > v1) { v2 = v1; v1 = probs[e]; }
            else if (probs[e] > v2) { v2 = probs[e]; }
        }
        if (v1 - v2 < EPS_GAP) {
            int p = atomicAdd(cnt2, 1);
            list2[p] = tokidx;
        }
        finalize_and_write(probs, cap,
                           out + (size_t)tokidx * NUM_E,
                           out + (size_t)NTOK * NUM_E + (size_t)tokidx * NUM_E);
    }
}

// Exact fp32 recompute for near-tie tokens, 512 threads, 2-way K-split
// (halves the serial k-chain; partials combined through LDS).
__launch_bounds__(512)
__global__ void recheck_kernel(const float* __restrict__ tokens,
                               const int* __restrict__ tarr,
                               const float* __restrict__ W1,
                               const float* __restrict__ b1,
                               const float* __restrict__ W2,
                               const float* __restrict__ b2,
                               float* __restrict__ out,
                               const int* __restrict__ cnt2,
                               const int* __restrict__ list2) {
    __shared__ float xs2[DIM];
    __shared__ float hp2[2][HID];
    __shared__ float hs2[HID];
    __shared__ float ls2[NUM_E];
    __shared__ float w2s2[HID * NUM_E];
    int tid = threadIdx.x;
    int n2 = cnt2[0];
    if (n2 == 0) return;
    for (int kk = tid; kk < HID * NUM_E; kk += 512) w2s2[kk] = W2[kk];
    const float kc = 0.70710678118654752f;
    int col = tid & 255;
    int kh = tid >> 8;                   // 0..1
    for (int i = blockIdx.x; i < n2; i += gridDim.x) {
        int tok = list2[i];
        __syncthreads();
        if (tid < 256)
            reinterpret_cast<float4*>(xs2)[tid] =
                reinterpret_cast<const float4*>(tokens + (size_t)tok * DIM)[tid];
        __syncthreads();
        float a = 0.0f;
        const float* wp = W1 + (size_t)kh * 512 * HID + col;
        const float* xp = xs2 + kh * 512;
#pragma unroll 8
        for (int k = 0; k < 512; ++k) a = fmaf(xp[k], wp[(size_t)k * HID], a);
        hp2[kh][col] = a;
        __syncthreads();
        if (tid < HID) {
            float pre = hp2[0][tid] + hp2[1][tid] + b1[tid];
            hs2[tid] = 0.5f * pre * (1.0f + erff(pre * kc));
        }
        __syncthreads();
        if (tid < NUM_E) {
            float s = 0.0f;
            for (int j = 0; j < HID; ++j) s = fmaf(hs2[j], w2s2[j * NUM_E + tid], s);
            ls2[tid] = (s + b2[tid]) / 0.1f;
        }
        __syncthreads();
        if (tid == 0) {
            int b = tok / NPB;
            float tnorm = (float)tarr[b] / 1000.0f;
            float cap = 0.5f + 1.1f * tnorm;
            float probs[NUM_E];
#pragma unroll
            for (int e = 0; e < NUM_E; ++e)
                probs[e] = ONE_MINUS_ALPHA * ls2[e] + FLOOR_TERM;
            finalize_and_write(probs, cap,
                               out + (size_t)tok * NUM_E,
                               out + (size_t)NTOK * NUM_E + (size_t)tok * NUM_E);
        }
    }
}

// Fallback (ws too small): round-20 fp32 kernel, proven 67.6 us total.
__launch_bounds__(512)
__global__ void mlp_fallback(const float* __restrict__ tokens,
                             const int* __restrict__ tarr,
                             const float* __restrict__ W1,
                             const float* __restrict__ b1,
                             const float* __restrict__ W2,
                             const float* __restrict__ b2,
                             float* __restrict__ out,
                             const int* __restrict__ cnt,
                             const int* __restrict__ list) {
    __shared__ float smem[8 * DIM];
    __shared__ float w2s[HID * NUM_E];
    __shared__ float ls[8][NUM_E];
    int count = cnt[0];
    int start = blockIdx.x * 8;
    if (count == 0 || start >= count) return;
    int tid = threadIdx.x;
    float (*xs)[DIM] = (float (*)[DIM])smem;
    {
        int slot = tid & 255;
        int rr = tid >> 8;
#pragma unroll
        for (int p = 0; p < 4; ++p) {
            int r = rr * 4 + p;
            int idx = start + r;
            if (idx > count - 1) idx = count - 1;
            int tok = list[idx];
            reinterpret_cast<float4*>(xs[r])[slot] =
                reinterpret_cast<const float4*>(tokens + (size_t)tok * DIM)[slot];
        }
    }
    for (int kk = tid; kk < HID * NUM_E; kk += 512) w2s[kk] = W2[kk];
    __syncthreads();
    int cg = tid & 63, ks = tid >> 6;
    int kbase = ks * 128, colbase = cg * 4;
    float acc[8][4];
#pragma unroll
    for (int r = 0; r < 8; ++r)
#pragma unroll
        for (int c = 0; c < 4; ++c) acc[r][c] = 0.0f;
    const float* w1p = W1 + (size_t)kbase * HID + colbase;
    const float* xbase = &xs[0][kbase];
#pragma unroll 2
    for (int k = 0; k < 128; k += 4) {
        float4 w[4];
        const float* wp = w1p + (size_t)k * HID;
#pragma unroll
        for (int kk = 0; kk < 4; ++kk)
            w[kk] = *reinterpret_cast<const float4*>(wp + kk * HID);
#pragma unroll
        for (int r = 0; r < 8; ++r) {
            float4 xq = *reinterpret_cast<const float4*>(xbase + r * DIM + k);
            acc[r][0] = fmaf(xq.x, w[0].x, acc[r][0]);
            acc[r][1] = fmaf(xq.x, w[0].y, acc[r][1]);
            acc[r][2] = fmaf(xq.x, w[0].z, acc[r][2]);
            acc[r][3] = fmaf(xq.x, w[0].w, acc[r][3]);
            acc[r][0] = fmaf(xq.y, w[1].x, acc[r][0]);
            acc[r][1] = fmaf(xq.y, w[1].y, acc[r][1]);
            acc[r][2] = fmaf(xq.y, w[1].z, acc[r][2]);
            acc[r][3] = fmaf(xq.y, w[1].w, acc[r][3]);
            acc[r][0] = fmaf(xq.z, w[2].x, acc[r][0]);
            acc[r][1] = fmaf(xq.z, w[2].y, acc[r][1]);
            acc[r][2] = fmaf(xq.z, w[2].z, acc[r][2]);
            acc[r][3] = fmaf(xq.z, w[2].w, acc[r][3]);
            acc[r][0] = fmaf(xq.w, w[3].x, acc[r][0]);
            acc[r][1] = fmaf(xq.w, w[3].y, acc[r][1]);
            acc[r][2] = fmaf(xq.w, w[3].z, acc[r][2]);
            acc[r][3] = fmaf(xq.w, w[3].w, acc[r][3]);
        }
    }
    __syncthreads();
    float (*hp)[HID] = (float (*)[HID])smem;
    float (*hs)[HID + 1] = (float (*)[HID + 1])(smem + 2048);
    const float kc = 0.70710678118654752f;
#pragma unroll 1
    for (int r = 0; r < 8; ++r) {
#pragma unroll
        for (int c = 0; c < 4; ++c) hp[ks][colbase + c] = acc[r][c];
        __syncthreads();
        if (tid < HID) {
            float s = hp[0][tid];
#pragma unroll
            for (int q = 1; q < 8; ++q) s += hp[q][tid];
            float pre = s + b1[tid];
            hs[r][tid] = 0.5f * pre * (1.0f + erff(pre * kc));
        }
        __syncthreads();
    }
    if (tid < 8 * NUM_E) {
        int r = tid / NUM_E, e = tid % NUM_E;
        float s = 0.0f;
        for (int j = 0; j < HID; ++j) s = fmaf(hs[r][j], w2s[j * NUM_E + e], s);
        ls[r][e] = (s + b2[e]) / 0.1f;
    }
    __syncthreads();
    if (tid < 8 && start + tid < count) {
        int tokidx = list[start + tid];
        int b = tokidx / NPB;
        float tnorm = (float)tarr[b] / 1000.0f;
        float cap = 0.5f + 1.1f * tnorm;
        float probs[NUM_E];
#pragma unroll
        for (int e = 0; e < NUM_E; ++e)
            probs[e] = ONE_MINUS_ALPHA * ls[tid][e] + FLOOR_TERM;
        finalize_and_write(probs, cap,
                           out + (size_t)tokidx * NUM_E,
                           out + (size_t)NTOK * NUM_E + (size_t)tokidx * NUM_E);
    }
}

extern "C" void kernel_launch(void* const* d_in, const int* in_sizes, int n_in,
                              void* d_out, int out_size, void* d_ws, size_t ws_size,
                              hipStream_t stream) {
    const float* tokens = (const float*)d_in[0];
    const int*   ttypes = (const int*)d_in[1];
    const int*   tarr   = (const int*)d_in[2];
    const float* W1     = (const float*)d_in[3];
    const float* b1     = (const float*)d_in[4];
    const float* W2     = (const float*)d_in[5];
    const float* b2     = (const float*)d_in[6];
    const float* base   = (const float*)d_in[7];
    float* out = (float*)d_out;

    char* ws = (char*)d_ws;
    int* cnt   = (int*)(ws + WS_CNT);
    int* cnt2  = (int*)(ws + WS_CNT2);
    int* list  = (int*)(ws + WS_LIST);
    int* list2 = (int*)(ws + WS_LIST2);

    hipMemsetAsync(ws, 0, 128, stream);
    classify_kernel<<<NTOK / 256, 256, 0, stream>>>(ttypes, tarr, base, out, cnt, list);

    if (ws_size >= WS_NEED) {
        unsigned short* wfh = (unsigned short*)(ws + WS_WFH);
        prep_w1<<<128, 256, 0, stream>>>(W1, wfh);
        mfma_mlp<<<NTOK / GRPM, 512, 0, stream>>>(tokens, tarr, wfh, b1, W2, b2,
                                                  out, cnt, list, cnt2, list2);
        recheck_kernel<<<256, 512, 0, stream>>>(tokens, tarr, W1, b1, W2, b2,
                                                out, cnt2, list2);
    } else {
        mlp_fallback<<<NTOK / 8, 512, 0, stream>>>(tokens, tarr, W1, b1, W2, b2,
                                                   out, cnt, list);
    }
}

// Round 24
// 66.017 us; speedup vs baseline: 1.2764x; 1.2764x over previous
//
#include <hip/hip_runtime.h>
#include <math.h>

#define NUM_E 6
#define DIM 1024
#define HID 256
#define NTOK 32768
#define NPB 4096   // tokens per batch (N)
#define TTYPE_UNKNOWN 5
#define ONE_MINUS_ALPHA 0.775f
#define FLOOR_TERM 0.0375f     // alpha * (1/E)
#define GRP 8                  // tokens per MLP block (683 working blocks; W1-reuse lever)
#define KSPLIT 8               // K segments (tid>>6), each 128 wide
#define KSPAN 128
#define CPT 4                  // consecutive columns per thread (float4 W1 loads)

// Closed-form top1 + hard-cap + combine for a probs vector of 6.
__device__ __forceinline__ void finalize_and_write(const float probs[NUM_E], float cap,
                                                   float* __restrict__ disp_out,
                                                   float* __restrict__ comb_out) {
    float v = probs[0];
    int bi = 0;
#pragma unroll
    for (int e = 1; e < NUM_E; ++e) {
        if (probs[e] > v) { v = probs[e]; bi = e; }
    }
    float excess = fmaxf(v - cap, 0.0f);
    float capped = v - excess;                 // min(v, cap)
    float hr_idx = fmaxf(cap - capped, 0.0f);
    float hsum = fmaxf(hr_idx + 5.0f * cap, 1e-8f);
    float disp[NUM_E];
    float other = excess * cap / hsum;
#pragma unroll
    for (int e = 0; e < NUM_E; ++e) disp[e] = other;
    disp[bi] = capped + excess * hr_idx / hsum;
    float s = 0.0f;
#pragma unroll
    for (int e = 0; e < NUM_E; ++e) s += disp[e];
    float inv = 1.0f / (s + 1e-8f);
#pragma unroll
    for (int e = 0; e < NUM_E; ++e) {
        disp_out[e] = disp[e];
        comb_out[e] = disp[e] * inv;
    }
}

// Known tokens -> final output directly; unknown -> compacted list.
__launch_bounds__(256)
__global__ void classify_kernel(const int* __restrict__ ttypes,
                                const int* __restrict__ tarr,
                                const float* __restrict__ base,
                                float* __restrict__ out,
                                int* __restrict__ cnt,
                                int* __restrict__ list) {
    int i = blockIdx.x * blockDim.x + threadIdx.x;
    if (i >= NTOK) return;
    int ty = ttypes[i];
    if (ty == TTYPE_UNKNOWN) {
        int pos = atomicAdd(cnt, 1);
        list[pos] = i;
        return;
    }
    int b = i / NPB;
    float tnorm = (float)tarr[b] / 1000.0f;
    float cap = 0.5f + 1.1f * tnorm;
    float probs[NUM_E];
#pragma unroll
    for (int e = 0; e < NUM_E; ++e)
        probs[e] = ONE_MINUS_ALPHA * base[ty * NUM_E + e] + FLOOR_TERM;
    finalize_and_write(probs, cap,
                       out + (size_t)i * NUM_E,
                       out + (size_t)NTOK * NUM_E + (size_t)i * NUM_E);
}

// Fused MLP gate, 512 threads = 8 waves, GRP=8 tokens staged once in 32 KB LDS.
// R20 proven shape (CPT=4, 44 VGPR, no spill, unroll 2). Epilogue processes
// TWO tokens per reduction pass (hp[8][2][256], all 512 threads reduce) ->
// 8 barriers instead of 16.
__launch_bounds__(512)
__global__ void mlp_kernel(const float* __restrict__ tokens,
                           const int* __restrict__ tarr,
                           const float* __restrict__ W1,
                           const float* __restrict__ b1,
                           const float* __restrict__ W2,
                           const float* __restrict__ b2,
                           float* __restrict__ out,
                           const int* __restrict__ cnt,
                           const int* __restrict__ list) {
    __shared__ float smem[GRP * DIM];    // 32 KB: xs in K-loop; hp+hs after
    __shared__ float w2s[HID * NUM_E];   // 6 KB
    __shared__ float ls[GRP][NUM_E];

    int count = cnt[0];
    int start = blockIdx.x * GRP;
    if (start >= count) return;
    int tid = threadIdx.x;

    float (*xs)[DIM] = (float (*)[DIM])smem;

    // Stage 8 token rows: 2048 float4 slots, 512 threads -> 4 each, coalesced.
    {
        int slot = tid & 255;            // float4 slot within a row
        int rr = tid >> 8;               // 0..1
#pragma unroll
        for (int p = 0; p < 4; ++p) {
            int r = rr * 4 + p;
            int idx = start + r;
            if (idx > count - 1) idx = count - 1;   // dup tail -> idempotent writes
            int tok = list[idx];
            const float4* src = reinterpret_cast<const float4*>(tokens + (size_t)tok * DIM);
            reinterpret_cast<float4*>(xs[r])[slot] = src[slot];
        }
    }
    for (int kk = tid; kk < HID * NUM_E; kk += 512) w2s[kk] = W2[kk];
    __syncthreads();

    int cg = tid & 63;                   // column group: cols [4cg, 4cg+4)
    int ks = tid >> 6;                   // 0..7
    int kbase = ks * KSPAN;
    int colbase = cg * CPT;

    float acc[GRP][CPT];
#pragma unroll
    for (int r = 0; r < GRP; ++r)
#pragma unroll
        for (int c = 0; c < CPT; ++c) acc[r][c] = 0.0f;

    const float* w1p = W1 + (size_t)kbase * HID + colbase;
    const float* xbase = &xs[0][kbase];  // + r*DIM + k at imm offsets (r static)

#pragma unroll 2
    for (int k = 0; k < KSPAN; k += 4) {
        // 4 coalesced float4 W1 loads (4 k-rows x one 4-col block)
        float4 w[4];
        const float* wp = w1p + (size_t)k * HID;
#pragma unroll
        for (int kk = 0; kk < 4; ++kk)
            w[kk] = *reinterpret_cast<const float4*>(wp + kk * HID);
        // 8 broadcast b128 x-reads (imm offsets), 128 FMA
#pragma unroll
        for (int r = 0; r < GRP; ++r) {
            float4 xq = *reinterpret_cast<const float4*>(xbase + r * DIM + k);
            acc[r][0] = fmaf(xq.x, w[0].x, acc[r][0]);
            acc[r][1] = fmaf(xq.x, w[0].y, acc[r][1]);
            acc[r][2] = fmaf(xq.x, w[0].z, acc[r][2]);
            acc[r][3] = fmaf(xq.x, w[0].w, acc[r][3]);
            acc[r][0] = fmaf(xq.y, w[1].x, acc[r][0]);
            acc[r][1] = fmaf(xq.y, w[1].y, acc[r][1]);
            acc[r][2] = fmaf(xq.y, w[1].z, acc[r][2]);
            acc[r][3] = fmaf(xq.y, w[1].w, acc[r][3]);
            acc[r][0] = fmaf(xq.z, w[2].x, acc[r][0]);
            acc[r][1] = fmaf(xq.z, w[2].y, acc[r][1]);
            acc[r][2] = fmaf(xq.z, w[2].z, acc[r][2]);
            acc[r][3] = fmaf(xq.z, w[2].w, acc[r][3]);
            acc[r][0] = fmaf(xq.w, w[3].x, acc[r][0]);
            acc[r][1] = fmaf(xq.w, w[3].y, acc[r][1]);
            acc[r][2] = fmaf(xq.w, w[3].z, acc[r][2]);
            acc[r][3] = fmaf(xq.w, w[3].w, acc[r][3]);
        }
    }
    __syncthreads();   // all xs reads done; re-purpose smem

    // aliased region (floats): hp[8][2][256] @0 (16 KB), hs[8][257] @4096
    float (*hp)[2][HID] = (float (*)[2][HID])smem;
    float (*hs)[HID + 1] = (float (*)[HID + 1])(smem + 4096);

    const float kc = 0.70710678118654752f;
#pragma unroll 1
    for (int r0 = 0; r0 < GRP; r0 += 2) {
        // write two tokens' partials: hp[ks][0/1][colbase..+3] (two b128)
#pragma unroll
        for (int c = 0; c < CPT; ++c) hp[ks][0][colbase + c] = acc[r0][c];
#pragma unroll
        for (int c = 0; c < CPT; ++c) hp[ks][1][colbase + c] = acc[r0 + 1][c];
        __syncthreads();
        {
            int tr = tid >> 8;           // 0..1 (token within pair)
            int col = tid & 255;
            float s = hp[0][tr][col];
#pragma unroll
            for (int q = 1; q < KSPLIT; ++q) s += hp[q][tr][col];
            float pre = s + b1[col];
            hs[r0 + tr][col] = 0.5f * pre * (1.0f + erff(pre * kc));
        }
        __syncthreads();
    }

    // Layer 2: 48 threads, one (token, expert) dot each
    if (tid < GRP * NUM_E) {
        int r = tid / NUM_E, e = tid % NUM_E;
        float s = 0.0f;
        for (int j = 0; j < HID; ++j) s = fmaf(hs[r][j], w2s[j * NUM_E + e], s);
        ls[r][e] = (s + b2[e]) / 0.1f;   // temperature
    }
    __syncthreads();

    // Finalize per token
    if (tid < GRP && start + tid < count) {
        int tokidx = list[start + tid];
        int b = tokidx / NPB;
        float tnorm = (float)tarr[b] / 1000.0f;
        float cap = 0.5f + 1.1f * tnorm;
        float probs[NUM_E];
#pragma unroll
        for (int e = 0; e < NUM_E; ++e)
            probs[e] = ONE_MINUS_ALPHA * ls[tid][e] + FLOOR_TERM;
        finalize_and_write(probs, cap,
                           out + (size_t)tokidx * NUM_E,
                           out + (size_t)NTOK * NUM_E + (size_t)tokidx * NUM_E);
    }
}

extern "C" void kernel_launch(void* const* d_in, const int* in_sizes, int n_in,
                              void* d_out, int out_size, void* d_ws, size_t ws_size,
                              hipStream_t stream) {
    const float* tokens = (const float*)d_in[0];
    const int*   ttypes = (const int*)d_in[1];
    const int*   tarr   = (const int*)d_in[2];
    const float* W1     = (const float*)d_in[3];
    const float* b1     = (const float*)d_in[4];
    const float* W2     = (const float*)d_in[5];
    const float* b2     = (const float*)d_in[6];
    const float* base   = (const float*)d_in[7];
    float* out = (float*)d_out;

    int* cnt  = (int*)d_ws;
    int* list = (int*)d_ws + 64;   // 256 B offset; list worst case 128 KB

    hipMemsetAsync(cnt, 0, sizeof(int), stream);
    classify_kernel<<<NTOK / 256, 256, 0, stream>>>(ttypes, tarr, base, out, cnt, list);
    mlp_kernel<<<NTOK / GRP, 512, 0, stream>>>(tokens, tarr, W1, b1, W2, b2,
                                               out, cnt, list);
}